// Round 7
// baseline (19.923 us; speedup 1.0000x reference)
//
#include <hip/hip_runtime.h>
#include <math.h>

#define NB 16
#define KB 32
#define KA 16
#define G  128
#define GP1 (G + 1)
#define ITERS 2

typedef float f4v __attribute__((ext_vector_type(4)));
typedef int   i4v __attribute__((ext_vector_type(4)));
typedef float f2v __attribute__((ext_vector_type(2)));

// ws layout (floats):
//   [0]=xlo  [1]=ginv=G/(xhi-xlo)  [2]=xhi  [3]=xlo*ginv  [4..63] pad
//   [64 ..]  float2 lut[NB][G] (dense, 16 KB): F_b(x) = c0 + c1*x on cell

__device__ __forceinline__ float softplus_f(float v) {
    return fmaxf(v, 0.0f) + log1pf(expf(-fabsf(v)));
}

// ---------------- kernel 1: 16 blocks, one bucket per block ----------------
__global__ __launch_bounds__(256) void build_lut_kernel(
    const float* __restrict__ x_mins,
    const float* __restrict__ x_maxs,
    const float* __restrict__ clip_los,
    const float* __restrict__ clip_his,
    const float* __restrict__ base_knots,
    const float* __restrict__ base_raw_w,
    const float* __restrict__ base_bias,
    const float* __restrict__ adj_knots,
    const float* __restrict__ adj_raw_w,
    const float* __restrict__ adj_bias,
    float* __restrict__ ws)
{
    __shared__ float s_bw[KB], s_bk[KB], s_aw[KA], s_ak[KA];
    __shared__ float s_x0[NB], s_x1[NB];
    __shared__ float s_prm[4];          // {a, c, Lb, Hb} for THIS block's bucket
    __shared__ float s_f[GP1];

    const int tid = threadIdx.x;
    const int b   = blockIdx.x;

    if (tid < KB) { s_bw[tid] = softplus_f(base_raw_w[tid]); s_bk[tid] = base_knots[tid]; }
    if (tid < KA) { s_aw[tid] = softplus_f(adj_raw_w[b * KA + tid]); s_ak[tid] = adj_knots[tid]; }
    if (tid < NB) {
        const float mn = x_mins[tid], mx = x_maxs[tid];
        const float inva = mx - mn + 1e-12f;
        const float a = 1.0f / inva;
        const float c = -mn * a;
        const float lo = clip_los[tid], hi = clip_his[tid];
        // fold clip bounds through monotone affine + [0,1] clamp;
        // non-finite bound => no clipping on that side
        const float Lb = isfinite(lo) ? fminf(fmaxf(fmaf(lo, a, c), 0.0f), 1.0f) : 0.0f;
        const float Hb = isfinite(hi) ? fmaxf(fminf(fmaf(hi, a, c), 1.0f), 0.0f) : 1.0f;
        // active x-range of bucket tid (F is constant outside)
        const float x0 = fmaf(Lb, inva, mn);
        const float x1 = fmaf(Hb, inva, mn);
        s_x0[tid] = fminf(x0, x1);
        s_x1[tid] = fmaxf(x0, x1);
        if (tid == b) { s_prm[0] = a; s_prm[1] = c; s_prm[2] = Lb; s_prm[3] = Hb; }
    }
    __syncthreads();

    float xlo = s_x0[0], xhi = s_x1[0];
    #pragma unroll
    for (int i = 1; i < NB; ++i) { xlo = fminf(xlo, s_x0[i]); xhi = fmaxf(xhi, s_x1[i]); }
    if (!(xhi > xlo)) xhi = xlo + 1.0f;            // degenerate guard
    const float ginv  = (float)G / (xhi - xlo);
    const float hstep = (xhi - xlo) * (1.0f / (float)G);

    if (b == 0 && tid == 0) {
        ws[0] = xlo; ws[1] = ginv; ws[2] = xhi; ws[3] = xlo * ginv;
    }

    if (tid < GP1) {
        const float xj = fmaf(hstep, (float)tid, xlo);
        const float v = fminf(fmaxf(fmaf(xj, s_prm[0], s_prm[1]), s_prm[2]), s_prm[3]);
        float f = adj_bias[b] + base_bias[0];
        #pragma unroll 8
        for (int k = 0; k < KB; ++k)
            f = fmaf(s_bw[k], fminf(v, s_bk[k]), f);
        #pragma unroll 8
        for (int k = 0; k < KA; ++k)
            f = fmaf(s_aw[k], fminf(v, s_ak[k]), f);
        s_f[tid] = f;
    }
    __syncthreads();

    if (tid < G) {
        const float fl = s_f[tid], fr = s_f[tid + 1];
        const float c1 = (fr - fl) * ginv;
        const float xj = fmaf(hstep, (float)tid, xlo);
        const float c0 = fmaf(-c1, xj, fl);
        ((f2v*)(ws + 64))[(b << 7) | tid] = (f2v){c0, c1};
    }
}

// ---------------- kernel 2: streaming eval, global-L1 LUT gather ----------------
__global__ __launch_bounds__(256) void BucketAdjustedHinge_kernel(
    const float* __restrict__ x,
    const int*   __restrict__ bucket_idx,
    const float* __restrict__ ws,
    float*       __restrict__ out,
    int n)
{
    const int tid = threadIdx.x;
    const int gsz = gridDim.x * blockDim.x;
    const int t   = blockIdx.x * blockDim.x + tid;
    const int n4  = n >> 2;

    const f4v* __restrict__ x4v = (const f4v*)x;
    const i4v* __restrict__ b4v = (const i4v*)bucket_idx;
    f4v*       __restrict__ o4v = (f4v*)out;
    const f2v* __restrict__ lut = (const f2v*)(ws + 64);

    // uniform params -> scalar loads
    const float xlo  = ws[0];
    const float ginv = ws[1];
    const float xhi  = ws[2];
    const float xlg  = ws[3];

    // streams are nontemporal so the 16 KB LUT stays L1-resident
    f4v xa[ITERS]; i4v ba[ITERS];
    #pragma unroll
    for (int k = 0; k < ITERS; ++k) {
        const int idx = t + k * gsz;
        if (idx < n4) {
            xa[k] = __builtin_nontemporal_load(x4v + idx);
            ba[k] = __builtin_nontemporal_load(b4v + idx);
        }
    }

    #define EVAL1(xr, b, dstf)                                             \
        {                                                                  \
            const float xc = fminf(fmaxf((xr), xlo), xhi);                 \
            const float tt = fmaf(xc, ginv, -xlg);                         \
            const int cell = min((int)tt, G - 1);                          \
            const f2v cf = lut[((b) << 7) | cell];                         \
            (dstf) = fmaf(xc, cf.y, cf.x);                                 \
        }

    #pragma unroll
    for (int k = 0; k < ITERS; ++k) {
        const int idx = t + k * gsz;
        if (idx < n4) {
            f4v r;
            EVAL1(xa[k].x, ba[k].x, r.x); EVAL1(xa[k].y, ba[k].y, r.y);
            EVAL1(xa[k].z, ba[k].z, r.z); EVAL1(xa[k].w, ba[k].w, r.w);
            __builtin_nontemporal_store(r, o4v + idx);
        }
    }

    // safety tails (unused when grid*ITERS covers n4 and n%4==0)
    for (int idx = t + ITERS * gsz; idx < n4; idx += gsz) {
        const f4v xv = __builtin_nontemporal_load(x4v + idx);
        const i4v bv = __builtin_nontemporal_load(b4v + idx);
        f4v r;
        EVAL1(xv.x, bv.x, r.x); EVAL1(xv.y, bv.y, r.y);
        EVAL1(xv.z, bv.z, r.z); EVAL1(xv.w, bv.w, r.w);
        __builtin_nontemporal_store(r, o4v + idx);
    }
    for (int i = (n4 << 2) + t; i < n; i += gsz) {
        float r;
        EVAL1(x[i], bucket_idx[i], r);
        out[i] = r;
    }
    #undef EVAL1
}

extern "C" void kernel_launch(void* const* d_in, const int* in_sizes, int n_in,
                              void* d_out, int out_size, void* d_ws, size_t ws_size,
                              hipStream_t stream) {
    const float* x          = (const float*)d_in[0];
    const float* x_mins     = (const float*)d_in[1];
    const float* x_maxs     = (const float*)d_in[2];
    const float* clip_los   = (const float*)d_in[3];
    const float* clip_his   = (const float*)d_in[4];
    const float* base_knots = (const float*)d_in[5];
    const float* base_raw_w = (const float*)d_in[6];
    const float* base_bias  = (const float*)d_in[7];
    const float* adj_knots  = (const float*)d_in[8];
    const float* adj_raw_w  = (const float*)d_in[9];
    const float* adj_bias   = (const float*)d_in[10];
    const int*   bucket_idx = (const int*)d_in[11];
    float* out = (float*)d_out;
    float* ws  = (float*)d_ws;

    const int n = in_sizes[0];

    build_lut_kernel<<<NB, 256, 0, stream>>>(
        x_mins, x_maxs, clip_los, clip_his,
        base_knots, base_raw_w, base_bias,
        adj_knots, adj_raw_w, adj_bias, ws);

    // no LDS in eval: 2048 blocks = 8 wg/CU, 8 waves/SIMD; ITERS=2 covers n4
    const int blocks = 2048;
    BucketAdjustedHinge_kernel<<<blocks, 256, 0, stream>>>(
        x, bucket_idx, ws, out, n);
}

// Round 8
// 18.954 us; speedup vs baseline: 1.0511x; 1.0511x over previous
//
#include <hip/hip_runtime.h>
#include <math.h>

#define NB 16
#define KB 32
#define KA 16
#define G  64
#define GP1 (G + 1)
#define ITERS 4

typedef float f4v __attribute__((ext_vector_type(4)));
typedef int   i4v __attribute__((ext_vector_type(4)));
typedef float f2v __attribute__((ext_vector_type(2)));

__device__ __forceinline__ float softplus_f(float v) {
    // numerically stable log(1 + exp(v))
    return fmaxf(v, 0.0f) + log1pf(expf(-fabsf(v)));
}

// Single fused kernel: every block builds the 16x64-cell PWL table for
// F_b(x) = f_b(clamp(affine_b(x))) in LDS (cheap: ~390 VALU/thread, hidden
// under the pre-issued stream-load latency), then streams 16 elements/thread
// through it: clamp -> cell index -> ds_read_b64 {c0,c1} -> fma.
__global__ __launch_bounds__(256) void BucketAdjustedHinge_kernel(
    const float* __restrict__ x,
    const float* __restrict__ x_mins,
    const float* __restrict__ x_maxs,
    const float* __restrict__ clip_los,
    const float* __restrict__ clip_his,
    const float* __restrict__ base_knots,
    const float* __restrict__ base_raw_w,
    const float* __restrict__ base_bias,
    const float* __restrict__ adj_knots,
    const float* __restrict__ adj_raw_w,
    const float* __restrict__ adj_bias,
    const int*   __restrict__ bucket_idx,
    float*       __restrict__ out,
    int n)
{
    __shared__ float  s_bw[KB], s_bk[KB], s_ak[KA];
    __shared__ float  s_aw[NB][KA + 1];     // +1 pad: pass-1 lanes differ in b
    __shared__ float4 s_abc[NB];            // {a, c, Lb, Hb}
    __shared__ float  s_bias[NB];
    __shared__ float  s_x0[NB], s_x1[NB];
    __shared__ float  s_fv[GP1][NB + 1];    // gridpoint values, +1 pad
    __shared__ f2v    s_lut[NB * G];        // dense: idx = (b<<6)|cell

    const int tid = threadIdx.x;
    const int gsz = gridDim.x * blockDim.x;
    const int t   = blockIdx.x * blockDim.x + tid;
    const int n4  = n >> 2;

    const f4v* __restrict__ x4v = (const f4v*)x;
    const i4v* __restrict__ b4v = (const i4v*)bucket_idx;
    f4v*       __restrict__ o4v = (f4v*)out;

    // ---- issue ALL stream loads first; their latency hides the LUT build ----
    f4v xa[ITERS]; i4v ba[ITERS];
    #pragma unroll
    for (int k = 0; k < ITERS; ++k) {
        const int idx = t + k * gsz;
        if (idx < n4) { xa[k] = x4v[idx]; ba[k] = b4v[idx]; }
    }

    // ---- stage params (small loads; queue behind the stream loads) ----
    if (tid < NB * KA) s_aw[tid >> 4][tid & (KA - 1)] = softplus_f(adj_raw_w[tid]);
    if (tid < KB) { s_bw[tid] = softplus_f(base_raw_w[tid]); s_bk[tid] = base_knots[tid]; }
    if (tid < KA) s_ak[tid] = adj_knots[tid];
    if (tid < NB) {
        const float mn = x_mins[tid], mx = x_maxs[tid];
        const float inva = mx - mn + 1e-12f;
        const float a = 1.0f / inva;
        const float c = -mn * a;
        const float lo = clip_los[tid], hi = clip_his[tid];
        // fold clip bounds through monotone affine + [0,1] clamp;
        // non-finite bound => no clipping on that side
        const float Lb = isfinite(lo) ? fminf(fmaxf(fmaf(lo, a, c), 0.0f), 1.0f) : 0.0f;
        const float Hb = isfinite(hi) ? fmaxf(fminf(fmaf(hi, a, c), 1.0f), 0.0f) : 1.0f;
        s_abc[tid] = make_float4(a, c, Lb, Hb);
        s_bias[tid] = adj_bias[tid] + base_bias[0];
        // active x-range of bucket (F_b exactly constant outside)
        const float x0 = fmaf(Lb, inva, mn);
        const float x1 = fmaf(Hb, inva, mn);
        s_x0[tid] = fminf(x0, x1);
        s_x1[tid] = fmaxf(x0, x1);
    }
    __syncthreads();

    // ---- global x-range (identical in every block; broadcast LDS reads) ----
    float xlo = s_x0[0], xhi = s_x1[0];
    #pragma unroll
    for (int i = 1; i < NB; ++i) { xlo = fminf(xlo, s_x0[i]); xhi = fmaxf(xhi, s_x1[i]); }
    if (!(xhi > xlo)) xhi = xlo + 1.0f;            // degenerate guard
    const float ginv  = (float)G / (xhi - xlo);    // 1/hstep
    const float hstep = (xhi - xlo) * (1.0f / (float)G);
    const float xlg   = xlo * ginv;

    // ---- pass 1: exact F_b at gridpoints; lanes: b = i&15 (conflict-free) ----
    for (int i = tid; i < NB * GP1; i += 256) {
        const int j = i >> 4, b = i & (NB - 1);
        const float xj = fmaf(hstep, (float)j, xlo);
        const float4 p = s_abc[b];
        const float v = fminf(fmaxf(fmaf(xj, p.x, p.y), p.z), p.w);
        float f = s_bias[b];
        #pragma unroll 8
        for (int k = 0; k < KB; ++k)
            f = fmaf(s_bw[k], fminf(v, s_bk[k]), f);
        #pragma unroll 8
        for (int k = 0; k < KA; ++k)
            f = fmaf(s_aw[b][k], fminf(v, s_ak[k]), f);
        s_fv[j][b] = f;
    }
    __syncthreads();

    // ---- pass 2: cell coefficients; i == (b<<6)|j so writes are linear ----
    for (int i = tid; i < NB * G; i += 256) {
        const int b = i >> 6, j = i & (G - 1);
        const float fl = s_fv[j][b], fr = s_fv[j + 1][b];
        const float c1 = (fr - fl) * ginv;
        const float xj = fmaf(hstep, (float)j, xlo);
        const float c0 = fmaf(-c1, xj, fl);
        s_lut[i] = (f2v){c0, c1};
    }
    __syncthreads();

    // ---- streaming evaluation ----
    #define EVAL1(xr, b, dstf)                                             \
        {                                                                  \
            const float xc = fminf(fmaxf((xr), xlo), xhi);                 \
            const float tt = fmaf(xc, ginv, -xlg);                         \
            const int cell = min((int)tt, G - 1);                          \
            const f2v cf = s_lut[((b) << 6) | cell];                       \
            (dstf) = fmaf(xc, cf.y, cf.x);                                 \
        }

    #pragma unroll
    for (int k = 0; k < ITERS; ++k) {
        const int idx = t + k * gsz;
        if (idx < n4) {
            f4v r;
            EVAL1(xa[k].x, ba[k].x, r.x); EVAL1(xa[k].y, ba[k].y, r.y);
            EVAL1(xa[k].z, ba[k].z, r.z); EVAL1(xa[k].w, ba[k].w, r.w);
            o4v[idx] = r;
        }
    }

    // safety tails (unused at N=4M: grid*ITERS covers n4 exactly, n%4==0)
    for (int idx = t + ITERS * gsz; idx < n4; idx += gsz) {
        const f4v xv = x4v[idx];
        const i4v bv = b4v[idx];
        f4v r;
        EVAL1(xv.x, bv.x, r.x); EVAL1(xv.y, bv.y, r.y);
        EVAL1(xv.z, bv.z, r.z); EVAL1(xv.w, bv.w, r.w);
        o4v[idx] = r;
    }
    for (int i = (n4 << 2) + t; i < n; i += gsz) {
        float r;
        EVAL1(x[i], bucket_idx[i], r);
        out[i] = r;
    }
    #undef EVAL1
}

extern "C" void kernel_launch(void* const* d_in, const int* in_sizes, int n_in,
                              void* d_out, int out_size, void* d_ws, size_t ws_size,
                              hipStream_t stream) {
    const float* x          = (const float*)d_in[0];
    const float* x_mins     = (const float*)d_in[1];
    const float* x_maxs     = (const float*)d_in[2];
    const float* clip_los   = (const float*)d_in[3];
    const float* clip_his   = (const float*)d_in[4];
    const float* base_knots = (const float*)d_in[5];
    const float* base_raw_w = (const float*)d_in[6];
    const float* base_bias  = (const float*)d_in[7];
    const float* adj_knots  = (const float*)d_in[8];
    const float* adj_raw_w  = (const float*)d_in[9];
    const float* adj_bias   = (const float*)d_in[10];
    const int*   bucket_idx = (const int*)d_in[11];
    float* out = (float*)d_out;

    const int n = in_sizes[0];
    // 1024 blocks x 256 thr x ITERS=4 float4-iters == n/4 exactly at N=4M
    const int blocks = 1024;
    BucketAdjustedHinge_kernel<<<blocks, 256, 0, stream>>>(
        x, x_mins, x_maxs, clip_los, clip_his,
        base_knots, base_raw_w, base_bias,
        adj_knots, adj_raw_w, adj_bias,
        bucket_idx, out, n);
}